// Round 14
// baseline (369.472 us; speedup 1.0000x reference)
//
#include <hip/hip_runtime.h>
#include <math.h>

#define N_CELLS 8192
#define DIM 512
#define TILE 128
#define BK 64
#define KITERS (DIM / BK)
#define NSTRIPE (N_CELLS / TILE)             // 64 stripes
#define NTRI (NSTRIPE * (NSTRIPE + 1) / 2)   // 2080 triangular blocks = 32*65
#define SAMPLE 1024        // sampled columns for the kth upper bound
#define CAP 384            // per-row candidate capacity (E[n]~120, P(ovf)~1e-8/row)
#define WQCAP 1024         // per-wave LDS hit queue entries (8KB/wave; expected ~120)

typedef float f32x4 __attribute__((ext_vector_type(4)));
typedef _Float16 f16x8 __attribute__((ext_vector_type(8)));

#define AS1U(p) ((const __attribute__((address_space(1))) unsigned int*)(p))
#define AS3U(p) ((__attribute__((address_space(3))) unsigned int*)(p))

// ---------- helpers: order-preserving float<->uint key ----------
__device__ __forceinline__ unsigned fkey(float f) {
    unsigned u = __float_as_uint(f);
    return (u & 0x80000000u) ? ~u : (u | 0x80000000u);
}
__device__ __forceinline__ float finv(unsigned k) {
    unsigned u = (k & 0x80000000u) ? (k ^ 0x80000000u) : ~k;
    return __uint_as_float(u);
}

// ---------- prep: norms + fp32->fp16 K-panel-major repack + zero out/done ----
// Efp layout: [kc][row][64] fp16 (kc = K/64 panel). Within each row's 64-elem
// chunk, 16B units are stored at unit^(row&7) — the T2 bank swizzle baked into
// the layout so linear global_load_lds staging yields conflict-free LDS reads.
__global__ __launch_bounds__(256) void prep_kernel(const float* __restrict__ E,
                                                   unsigned short* __restrict__ Efp,
                                                   float* __restrict__ norms,
                                                   float* __restrict__ out,
                                                   unsigned* __restrict__ done) {
    if (blockIdx.x == 0 && threadIdx.x == 0) { out[0] = 0.0f; done[0] = 0u; }
    const int wave = threadIdx.x >> 6, lane = threadIdx.x & 63;
    const int row = blockIdx.x * 4 + wave;
    const float4* e4 = (const float4*)(E + (size_t)row * DIM);
    float4 a = e4[lane * 2], b = e4[lane * 2 + 1];      // elems [lane*8, lane*8+8)
    f16x8 h;
    h[0] = (_Float16)a.x; h[1] = (_Float16)a.y; h[2] = (_Float16)a.z; h[3] = (_Float16)a.w;
    h[4] = (_Float16)b.x; h[5] = (_Float16)b.y; h[6] = (_Float16)b.z; h[7] = (_Float16)b.w;
    const int kc = lane >> 3;                            // K-panel 0..7
    const int u  = lane & 7;                             // 16B unit within panel-row
    *(f16x8*)(Efp + ((size_t)kc * N_CELLS + row) * 64 + (size_t)(u ^ (row & 7)) * 8) = h;
    float s = a.x*a.x + a.y*a.y + a.z*a.z + a.w*a.w
            + b.x*b.x + b.y*b.y + b.z*b.z + b.w*b.w;
    #pragma unroll
    for (int off = 32; off > 0; off >>= 1) s += __shfl_down(s, off, 64);
    if (lane == 0) norms[row] = s;
}

// ---------- legacy norms-only (tiny-ws fallback path) ----------
__global__ __launch_bounds__(256) void norms_kernel(const float* __restrict__ E,
                                                    float* __restrict__ norms,
                                                    float* __restrict__ out) {
    if (blockIdx.x == 0 && threadIdx.x == 0) out[0] = 0.0f;
    const int wave = threadIdx.x >> 6, lane = threadIdx.x & 63;
    const int row = blockIdx.x * 4 + wave;
    const float4* e4 = (const float4*)(E + (size_t)row * DIM);
    float4 a = e4[lane], b = e4[lane + 64];
    float s = a.x*a.x + a.y*a.y + a.z*a.z + a.w*a.w
            + b.x*b.x + b.y*b.y + b.z*b.z + b.w*b.w;
    #pragma unroll
    for (int off = 32; off > 0; off >>= 1) s += __shfl_down(s, off, 64);
    if (lane == 0) norms[row] = s;
}

// ====== packed-panel BK=64 GEMM core, 2-iteration jam (R11 proven config) ====
// Staging: fully-contiguous 1KB/wave-instruction reads from Efp panels into
// linear tiles. Buffer pair p at smem + p*32768: A [0,16K), B [16K,32K).
// Per jam-step: stage BOTH buffer pairs (16 loads/thread), ONE barrier+drain,
// then 2x compute back-to-back. Fragment reads XOR the lane-constant
// fx=(fr&7)<<4 to undo the baked swizzle.

#define STAGE_PACKED(BUF, it)                                                                     \
    do {                                                                                          \
        const unsigned short* pa_ = Efp + ((size_t)(it) * N_CELLS + arow) * 64;                   \
        const unsigned short* pb_ = Efp + ((size_t)(it) * N_CELLS + brow) * 64;                   \
        _Pragma("unroll")                                                                         \
        for (int q_ = 0; q_ < 4; q_++) {                                                          \
            __builtin_amdgcn_global_load_lds(AS1U(pa_ + q_*2048 + t*8),                           \
                                             AS3U((BUF) + q_*4096 + t*16), 16, 0, 0);             \
            __builtin_amdgcn_global_load_lds(AS1U(pb_ + q_*2048 + t*8),                           \
                                             AS3U((BUF) + 16384 + q_*4096 + t*16), 16, 0, 0);     \
        }                                                                                         \
    } while (0)

#define GEMM_COMPUTE(BUF)                                                                         \
    do {                                                                                          \
        _Pragma("unroll")                                                                         \
        for (int ks = 0; ks < 2; ks++) {                                                          \
            f16x8 af[4], bf[4];                                                                   \
            _Pragma("unroll")                                                                     \
            for (int tm = 0; tm < 4; tm++)                                                        \
                af[tm] = *(const f16x8*)((BUF) + (size_t)(wr*64 + tm*16 + fr) * 128               \
                                              + (((ks*4 + kg) * 16) ^ fx));                       \
            _Pragma("unroll")                                                                     \
            for (int tn = 0; tn < 4; tn++)                                                        \
                bf[tn] = *(const f16x8*)((BUF) + 16384 + (size_t)(wc*64 + tn*16 + fr) * 128       \
                                              + (((ks*4 + kg) * 16) ^ fx));                       \
            _Pragma("unroll")                                                                     \
            for (int tm = 0; tm < 4; tm++)                                                        \
                _Pragma("unroll")                                                                 \
                for (int tn = 0; tn < 4; tn++)                                                    \
                    acc[tm][tn] = __builtin_amdgcn_mfma_f32_16x16x32_f16(af[tm], bf[tn],          \
                                                                         acc[tm][tn], 0, 0, 0);  \
        }                                                                                         \
    } while (0)

#define GEMM_LOOP()                                                                               \
    do {                                                                                          \
        _Pragma("unroll")                                                                         \
        for (int it2 = 0; it2 < KITERS; it2 += 2) {                                               \
            __syncthreads();                                                                      \
            STAGE_PACKED(smem, it2);                                                              \
            STAGE_PACKED(smem + 32768, it2 + 1);                                                  \
            __syncthreads();                                                                      \
            GEMM_COMPUTE(smem);                                                                   \
            GEMM_COMPUTE(smem + 32768);                                                           \
        }                                                                                         \
        __syncthreads();                                                                          \
    } while (0)

// ---------- sample GEMM: distances for cols [0,SAMPLE), writes Dsamp ----------
// Bitwise-identical MFMA chain to main_cand (same Efp panels, same fragment
// order, same BK sequence) so the sampled 15th is a valid >= bound on the
// full-row 15th; the dot is bitwise symmetric (products commute; k-order
// fixed), so main's triangular orientation reproduces these exact values.
__global__ __launch_bounds__(256) void samp_dist_kernel(const unsigned short* __restrict__ Efp,
                                                        const float* __restrict__ norms,
                                                        float* __restrict__ Dsamp) {
    __shared__ __align__(16) char smem[65536];

    const int t = threadIdx.x;
    const int lane = t & 63;
    const int w = t >> 6;
    const int wr = w >> 1, wc = w & 1;

    const int arow = blockIdx.y * TILE;
    const int brow = blockIdx.x * TILE;     // < SAMPLE

    const int kg = lane >> 4;
    const int fr = lane & 15;
    const int fx = (fr & 7) << 4;

    f32x4 acc[4][4];
    #pragma unroll
    for (int a = 0; a < 4; a++)
        #pragma unroll
        for (int b = 0; b < 4; b++)
            acc[a][b] = (f32x4){0.f, 0.f, 0.f, 0.f};

    GEMM_LOOP();

    const int colb = brow + wc * 64 + fr;
    const int rowb = arow + wr * 64 + (lane >> 4) * 4;
    #pragma unroll
    for (int tn = 0; tn < 4; tn++) {
        const int col = colb + tn * 16;
        const float nj = norms[col];
        #pragma unroll
        for (int tm = 0; tm < 4; tm++) {
            #pragma unroll
            for (int r = 0; r < 4; r++) {
                const int row = rowb + tm * 16 + r;
                float d = norms[row] + nj - 2.0f * acc[tm][tn][r];
                if (row == col) d += 1e10f;
                Dsamp[(size_t)row * SAMPLE + col] = d;
            }
        }
    }
}

// ---------- T-select: exact 15th smallest of each sampled row (1024 elems) ---
// 4 rows per 256-thread block (one row per wave). Sort-free: count-based
// bit search between row min and row max; T[row] >= true full-row 15th.
__global__ __launch_bounds__(256) void tsel_kernel(const float* __restrict__ Dsamp,
                                                   float* __restrict__ T,
                                                   int* __restrict__ cnt) {
    const int row = blockIdx.x * 4 + (threadIdx.x >> 6);
    const int lane = threadIdx.x & 63;
    const float4* r4 = (const float4*)(Dsamp + (size_t)row * SAMPLE);

    float v[16];
    #pragma unroll
    for (int s = 0; s < 4; s++) {
        float4 d4 = r4[s * 64 + lane];
        v[s*4+0] = d4.x; v[s*4+1] = d4.y; v[s*4+2] = d4.z; v[s*4+3] = d4.w;
    }
    float mn = v[0], mx = v[0];
    #pragma unroll
    for (int k = 1; k < 16; k++) { mn = fminf(mn, v[k]); mx = fmaxf(mx, v[k]); }
    #pragma unroll
    for (int off = 32; off > 0; off >>= 1) {
        mn = fminf(mn, __shfl_down(mn, off, 64));
        mx = fmaxf(mx, __shfl_down(mx, off, 64));
    }
    mn = __shfl(mn, 0, 64);
    mx = __shfl(mx, 0, 64);

    unsigned lo = fkey(mn), hi = fkey(mx);   // count(<=mx)=1024 >= 15
    int it = 0;
    while (lo < hi && it < 34) {
        it++;
        const unsigned mid = lo + ((hi - lo) >> 1);
        const float fm = finv(mid);
        int c = 0;
        #pragma unroll
        for (int k = 0; k < 16; k++) c += (v[k] <= fm) ? 1 : 0;
        #pragma unroll
        for (int off = 32; off > 0; off >>= 1) c += __shfl_down(c, off, 64);
        c = __shfl(c, 0, 64);
        if (c >= 15) hi = mid; else lo = mid + 1;
    }
    if (lane == 0) { T[row] = finv(lo); cnt[row] = 0; }
}

// ---------- main GEMM: folded triangular grid (2080 = 32x65), both dirs ------
// Fold: pair row y with row 63-y so every 65 consecutive fids form one
// constant-width epoch touching exactly TWO A-stripes (256 KB, L2-resident)
// while B walks from col 0. fid -> y=fid/65, x=fid%65;
// x<=y ? (a,b)=(y,x) : (a,b)=(63-y,x-y-1).
// Pair (i,j) computed ONCE (dot bitwise symmetric): d serves row i
// (label=labels[j]) AND row j (label=labels[i]). Diagonal tiles gate row>col.
__global__ __launch_bounds__(256) void main_cand_kernel(const unsigned short* __restrict__ Efp,
                                                        const float* __restrict__ norms,
                                                        const int* __restrict__ labels,
                                                        const float* __restrict__ T,
                                                        int* __restrict__ cnt,
                                                        int2* __restrict__ cand) {
    __shared__ __align__(16) char smem[65536];

    const int t = threadIdx.x;
    const int lane = t & 63;
    const int w = t >> 6;
    const int wr = w >> 1, wc = w & 1;

    // folded triangular index -> (a,b), a >= b
    const int fid = blockIdx.x;
    const int y = fid / 65;
    const int x = fid - y * 65;
    const int a = (x <= y) ? y : (NSTRIPE - 1 - y);
    const int b = (x <= y) ? x : (x - y - 1);

    const int arow = a * TILE;               // row stripe (>= col stripe)
    const int brow = b * TILE;               // col stripe
    const bool diag = (a == b);

    const int kg = lane >> 4;
    const int fr = lane & 15;
    const int fx = (fr & 7) << 4;

    f32x4 acc[4][4];
    #pragma unroll
    for (int aa = 0; aa < 4; aa++)
        #pragma unroll
        for (int bb = 0; bb < 4; bb++)
            acc[aa][bb] = (f32x4){0.f, 0.f, 0.f, 0.f};

    GEMM_LOOP();   // trailing __syncthreads: tiles dead -> smem reusable

    // ---- epilogue ----
    int2* wq = (int2*)(smem + (size_t)w * 8192);   // wave-private 1024 entries

    const int colb = brow + wc * 64 + fr;
    const int rowb = arow + wr * 64 + (lane >> 4) * 4;

    // per-thread constants (static indexing -> registers)
    float Trow[4][4], Nrow[4][4];
    int Lrow[4][4];
    #pragma unroll
    for (int tm = 0; tm < 4; tm++)
        #pragma unroll
        for (int r = 0; r < 4; r++) {
            const int row = rowb + tm * 16 + r;
            Trow[tm][r] = T[row];
            Nrow[tm][r] = norms[row];
            Lrow[tm][r] = labels[row];
        }
    float Tcol[4];
    #pragma unroll
    for (int tn = 0; tn < 4; tn++) Tcol[tn] = T[colb + tn * 16];

    int wn = 0;   // wave-uniform queue count
    #pragma unroll
    for (int tn = 0; tn < 4; tn++) {
        const int col = colb + tn * 16;
        const float nj = norms[col];
        const int labc = labels[col];
        #pragma unroll
        for (int tm = 0; tm < 4; tm++) {
            #pragma unroll
            for (int r = 0; r < 4; r++) {
                const int row = rowb + tm * 16 + r;
                const float d = Nrow[tm][r] + nj - 2.0f * acc[tm][tn][r];
                const bool live = !diag || (row > col);   // excludes row==col
                // direction A: candidate for row `row`, label = labels[col]
                {
                    const bool hit = live && (d <= Trow[tm][r]);
                    const unsigned long long bal = __ballot(hit);
                    if (hit) {
                        const int pos = __popcll(bal & ((1ull << lane) - 1ull));
                        if (wn + pos < WQCAP)
                            wq[wn + pos] = make_int2(__float_as_int(d), row | (labc << 13));
                    }
                    wn += (int)__popcll(bal);
                }
                // direction B: candidate for row `col`, label = labels[row]
                {
                    const bool hit = live && (d <= Tcol[tn]);
                    const unsigned long long bal = __ballot(hit);
                    if (hit) {
                        const int pos = __popcll(bal & ((1ull << lane) - 1ull));
                        if (wn + pos < WQCAP)
                            wq[wn + pos] = make_int2(__float_as_int(d), col | (Lrow[tm][r] << 13));
                    }
                    wn += (int)__popcll(bal);
                }
            }
        }
    }

    // flush own segment (independent per-thread global atomics)
    const int qn = (wn < WQCAP) ? wn : WQCAP;
    for (int i = lane; i < qn; i += 64) {
        const int2 e = wq[i];
        const int row = e.y & 8191;
        const int lab = e.y >> 13;
        const int idx = atomicAdd(&cnt[row], 1);
        if (idx < CAP) cand[(size_t)row * CAP + idx] = make_int2(e.x, lab);
    }
    // overflow (never expected): poison both stripes -> exact fallback
    if (wn > WQCAP)
        for (int r2 = lane; r2 < TILE; r2 += 64) {
            atomicAdd(&cnt[arow + r2], 1000000);
            atomicAdd(&cnt[brow + r2], 1000000);
        }
}

// ---------- finalize: exact kth + truncated sums -> rowloss; fused reduce ----
// 4 rows per 256-thread block (one per wave); no same-address atomics.
// Rows with bad cnt were already written by the insurance kernel (launched
// BEFORE final in stream order). Last block (done counter) sums rowloss->out.
// Truncation error <= 8192*exp(-(T-dmin)) ~ e^-40 — below fp32 ulp.
__global__ __launch_bounds__(256) void final_kernel(const int2* __restrict__ cand,
                                                    const int* __restrict__ cnt,
                                                    const float* __restrict__ T,
                                                    float* __restrict__ rowloss,
                                                    float* __restrict__ out,
                                                    unsigned* __restrict__ done) {
    __shared__ bool isLast;
    __shared__ float wsum[4];
    const int row = blockIdx.x * 4 + (threadIdx.x >> 6);
    const int lane = threadIdx.x & 63;
    const int wv = threadIdx.x >> 6;
    const int n = cnt[row];

    if (n >= 15 && n <= CAP) {
        float d[CAP / 64];
        int lb[CAP / 64];
        #pragma unroll
        for (int s = 0; s < CAP / 64; s++) {
            const int idx = s * 64 + lane;
            if (idx < n) {
                const int2 c = cand[(size_t)row * CAP + idx];
                d[s] = __int_as_float(c.x);
                lb[s] = c.y;
            } else { d[s] = 3.0e38f; lb[s] = 3; }
        }

        float dmin = d[0];
        #pragma unroll
        for (int s = 1; s < CAP / 64; s++) dmin = fminf(dmin, d[s]);
        #pragma unroll
        for (int off = 32; off > 0; off >>= 1) dmin = fminf(dmin, __shfl_down(dmin, off, 64));
        dmin = __shfl(dmin, 0, 64);

        unsigned lo = fkey(dmin), hi = fkey(T[row]);   // count(<=T) = n >= 15
        int it = 0;
        while (lo < hi && it < 34) {
            it++;
            const unsigned mid = lo + ((hi - lo) >> 1);
            const float fm = finv(mid);
            int c = 0;
            #pragma unroll
            for (int s = 0; s < CAP / 64; s++) c += (d[s] <= fm) ? 1 : 0;
            #pragma unroll
            for (int off = 32; off > 0; off >>= 1) c += __shfl_down(c, off, 64);
            c = __shfl(c, 0, 64);
            if (c >= 15) hi = mid; else lo = mid + 1;
        }
        const float kth = finv(lo);

        float z = 0.f, s0 = 0.f, s1 = 0.f, s2 = 0.f;
        #pragma unroll
        for (int s = 0; s < CAP / 64; s++) {
            const float w = __expf(dmin - d[s]);              // sentinel -> 0
            const float msk = 1.0f / (1.0f + __expf(d[s] - kth));
            const float p = w * msk;
            z  += w;
            s0 += (lb[s] == 0) ? p : 0.f;
            s1 += (lb[s] == 1) ? p : 0.f;
            s2 += (lb[s] == 2) ? p : 0.f;
        }
        #pragma unroll
        for (int off = 32; off > 0; off >>= 1) {
            z  += __shfl_down(z,  off, 64);
            s0 += __shfl_down(s0, off, 64);
            s1 += __shfl_down(s1, off, 64);
            s2 += __shfl_down(s2, off, 64);
        }
        if (lane == 0) {
            const float ssum = s0 + s1 + s2;
            const float denom = ssum + 1e-8f * z;
            const float q0 = s0/denom, q1 = s1/denom, q2 = s2/denom;
            const float H = -(q0*logf(q0+1e-8f) + q1*logf(q1+1e-8f) + q2*logf(q2+1e-8f));
            rowloss[row] = -(H / (logf(3.0f) + 1e-8f)) * (1.0f / N_CELLS);
        }
    }
    // rows with bad cnt: rowloss already written by insurance kernel (earlier
    // in stream). Fall through to the completion protocol.

    __threadfence();
    __syncthreads();
    if (threadIdx.x == 0) {
        const unsigned r = atomicAdd(done, 1u);
        isLast = (r == (unsigned)(gridDim.x - 1));
    }
    __syncthreads();
    if (isLast) {
        __threadfence();   // acquire: see all rowloss stores
        const float4* r4 = (const float4*)rowloss;
        float s = 0.f;
        for (int i = threadIdx.x; i < N_CELLS / 4; i += 256) {
            const float4 v = r4[i];
            s += v.x + v.y + v.z + v.w;
        }
        #pragma unroll
        for (int off = 32; off > 0; off >>= 1) s += __shfl_down(s, off, 64);
        if (lane == 0) wsum[wv] = s;
        __syncthreads();
        if (threadIdx.x == 0)
            out[0] = wsum[0] + wsum[1] + wsum[2] + wsum[3];
    }
}

// ---------- shared tail for fused fallback ----------
// rowloss != nullptr: store per-row contrib (main path insurance).
// rowloss == nullptr: atomicAdd to out (tiny-ws full mode).
template<int NT>
__device__ __forceinline__ void finish_row(const float* rowb,
                                           float lst[15],
                                           const int* __restrict__ labels,
                                           float* __restrict__ out,
                                           float* __restrict__ rowloss,
                                           int rowidx) {
    constexpr int WAVES = NT / 64;
    __shared__ float w0s[WAVES], w14s[WAVES];
    __shared__ int cnt;
    __shared__ float zz[WAVES], r0s[WAVES], r1s[WAVES], r2s[WAVES];

    const int t = threadIdx.x;
    const int lane = t & 63, wave = t >> 6;

    float m0 = lst[0], m14 = lst[14];
    #pragma unroll
    for (int off = 32; off > 0; off >>= 1) {
        m0  = fminf(m0,  __shfl_down(m0,  off, 64));
        m14 = fminf(m14, __shfl_down(m14, off, 64));
    }
    if (lane == 0) { w0s[wave] = m0; w14s[wave] = m14; }
    __syncthreads();
    float dmin = w0s[0], ub = w14s[0];
    #pragma unroll
    for (int i = 1; i < WAVES; i++) { dmin = fminf(dmin, w0s[i]); ub = fminf(ub, w14s[i]); }

    unsigned lo = fkey(dmin), hi = fkey(ub);
    int iter = 0;
    while (lo < hi && iter < 34) {
        iter++;
        const unsigned mid = lo + ((hi - lo) >> 1);
        const float fmid = finv(mid);
        int c = 0;
        #pragma unroll
        for (int k = 0; k < 15; k++) c += (lst[k] <= fmid) ? 1 : 0;
        #pragma unroll
        for (int off = 32; off > 0; off >>= 1) c += __shfl_down(c, off, 64);
        __syncthreads();
        if (t == 0) cnt = 0;
        __syncthreads();
        if (lane == 0) atomicAdd(&cnt, c);
        __syncthreads();
        const int total = cnt;
        if (total >= 15) hi = mid; else lo = mid + 1;
    }
    const float kth = finv(hi);

    const float4* rb4 = (const float4*)rowb;
    const int4* lb4 = (const int4*)labels;
    float z = 0.f, s0 = 0.f, s1 = 0.f, s2 = 0.f;
    #pragma unroll
    for (int s = 0; s < N_CELLS / (4 * NT); s++) {
        const int idx = s * NT + t;
        const float4 d4 = rb4[idx];
        const int4 l4 = lb4[idx];
        #pragma unroll
        for (int c2 = 0; c2 < 4; c2++) {
            const float d = (c2 == 0) ? d4.x : (c2 == 1) ? d4.y : (c2 == 2) ? d4.z : d4.w;
            const int lab = (c2 == 0) ? l4.x : (c2 == 1) ? l4.y : (c2 == 2) ? l4.z : l4.w;
            const float w = __expf(dmin - d);
            const float msk = 1.0f / (1.0f + __expf(d - kth));
            const float p = w * msk;
            z  += w;
            s0 += (lab == 0) ? p : 0.f;
            s1 += (lab == 1) ? p : 0.f;
            s2 += (lab == 2) ? p : 0.f;
        }
    }
    #pragma unroll
    for (int off = 32; off > 0; off >>= 1) {
        z  += __shfl_down(z,  off, 64);
        s0 += __shfl_down(s0, off, 64);
        s1 += __shfl_down(s1, off, 64);
        s2 += __shfl_down(s2, off, 64);
    }
    if (lane == 0) { zz[wave] = z; r0s[wave] = s0; r1s[wave] = s1; r2s[wave] = s2; }
    __syncthreads();
    if (t == 0) {
        float Z = 0.f, S0 = 0.f, S1 = 0.f, S2 = 0.f;
        #pragma unroll
        for (int i = 0; i < WAVES; i++) { Z += zz[i]; S0 += r0s[i]; S1 += r1s[i]; S2 += r2s[i]; }
        const float ssum = S0 + S1 + S2;
        const float denom = ssum + 1e-8f * Z;
        const float q0 = S0/denom, q1 = S1/denom, q2 = S2/denom;
        const float H = -(q0*logf(q0+1e-8f) + q1*logf(q1+1e-8f) + q2*logf(q2+1e-8f));
        const float contrib = -(H / (logf(3.0f) + 1e-8f)) * (1.0f / N_CELLS);
        if (rowloss) rowloss[rowidx] = contrib;
        else atomicAdd(out, contrib);
    }
}

// ---------- fused fp32 full-row recompute (exact) ----------
__device__ void process_row(int i,
                            const float* __restrict__ E,
                            const float* __restrict__ norms,
                            const int* __restrict__ labels,
                            float* __restrict__ out,
                            float* __restrict__ rowloss,
                            float* rowb, float* ei) {
    const int t = threadIdx.x;
    __syncthreads();
    for (int k = t; k < DIM; k += 512) ei[k] = E[(size_t)i * DIM + k];
    __syncthreads();
    const float ni = norms[i];

    float lst[15];
    #pragma unroll
    for (int k = 0; k < 15; k++) lst[k] = 3.0e38f;

    for (int s = 0; s < N_CELLS / 512; s++) {
        const int j = s * 512 + t;
        const float* ej = E + (size_t)j * DIM;
        float dot = 0.f;
        #pragma unroll 4
        for (int k = 0; k < DIM; k += 4) {
            float4 e4 = *(const float4*)(ej + k);
            dot += ei[k]*e4.x + ei[k+1]*e4.y + ei[k+2]*e4.z + ei[k+3]*e4.w;
        }
        float d = ni + norms[j] - 2.0f * dot;
        if (j == i) d += 1e10f;
        rowb[j] = d;
        float v = d;
        #pragma unroll
        for (int k = 0; k < 15; k++) {
            float lo2 = fminf(lst[k], v);
            v = fmaxf(lst[k], v);
            lst[k] = lo2;
        }
    }
    finish_row<512>(rowb, lst, labels, out, rowloss, i);
}

// cnt_g == nullptr: tiny-ws full mode (grid N_CELLS, one row per block,
// atomic accumulate to out). cnt_g != nullptr: insurance mode (grid 64):
// scan 128 rows each, process only failed rows (~never), store to rowloss.
__global__ __launch_bounds__(512) void fused_kernel(const float* __restrict__ E,
                                                    const float* __restrict__ norms,
                                                    const int* __restrict__ labels,
                                                    float* __restrict__ out,
                                                    float* __restrict__ rowloss,
                                                    const int* __restrict__ cnt_g) {
    __shared__ float rowb[N_CELLS];
    __shared__ float ei[DIM];
    __shared__ int bad[TILE];
    __shared__ int nbad;
    const int t = threadIdx.x;

    if (cnt_g == nullptr) {
        process_row(blockIdx.x, E, norms, labels, out, nullptr, rowb, ei);
        return;
    }
    if (t == 0) nbad = 0;
    __syncthreads();
    if (t < TILE) {
        const int row = blockIdx.x * TILE + t;
        const int n = cnt_g[row];
        if (n < 15 || n > CAP) bad[atomicAdd(&nbad, 1)] = row;
    }
    __syncthreads();
    const int nb = nbad;
    for (int b = 0; b < nb; b++)
        process_row(bad[b], E, norms, labels, out, rowloss, rowb, ei);
}

// ---------- launcher ----------
// ws: norms 32KB | Efp fp16 8MB | T 32KB | cnt 32KB | rowloss 32KB | done 4KB
//     | Dsamp 32MB | cand 25MB
extern "C" void kernel_launch(void* const* d_in, const int* in_sizes, int n_in,
                              void* d_out, int out_size, void* d_ws, size_t ws_size,
                              hipStream_t stream) {
    const float* E = (const float*)d_in[0];
    const int* labels = (const int*)d_in[1];
    float* out = (float*)d_out;

    char* p = (char*)d_ws;
    float* norms = (float*)p;                 p += 32768;
    unsigned short* Efp = (unsigned short*)p; p += (size_t)N_CELLS * DIM * 2;
    float* T = (float*)p;                     p += 32768;
    int* cnt = (int*)p;                       p += 32768;
    float* rowloss = (float*)p;               p += 32768;
    unsigned* done = (unsigned*)p;            p += 4096;
    float* Dsamp = (float*)p;                 p += (size_t)N_CELLS * SAMPLE * 4;
    int2* cand = (int2*)p;                    p += (size_t)N_CELLS * CAP * 8;
    const size_t need = (size_t)(p - (char*)d_ws);

    if (ws_size >= need) {
        prep_kernel<<<N_CELLS / 4, 256, 0, stream>>>(E, Efp, norms, out, done);
        samp_dist_kernel<<<dim3(SAMPLE / TILE, N_CELLS / TILE), 256, 0, stream>>>(Efp, norms, Dsamp);
        tsel_kernel<<<N_CELLS / 4, 256, 0, stream>>>(Dsamp, T, cnt);
        main_cand_kernel<<<NTRI, 256, 0, stream>>>(Efp, norms, labels, T, cnt, cand);
        fused_kernel<<<N_CELLS / TILE, 512, 0, stream>>>(E, norms, labels, out, rowloss, cnt);  // insurance
        final_kernel<<<N_CELLS / 4, 256, 0, stream>>>(cand, cnt, T, rowloss, out, done);        // + reduce
    } else {
        norms_kernel<<<N_CELLS / 4, 256, 0, stream>>>(E, norms, out);
        fused_kernel<<<N_CELLS, 512, 0, stream>>>(E, norms, labels, out, nullptr, nullptr);
    }
}

// Round 16
// 254.858 us; speedup vs baseline: 1.4497x; 1.4497x over previous
//
#include <hip/hip_runtime.h>
#include <math.h>

#define N_CELLS 8192
#define DIM 512
#define TILE 128
#define BK 64
#define KITERS (DIM / BK)
#define NSTRIPE (N_CELLS / TILE)             // 64 stripes
#define NTRI (NSTRIPE * (NSTRIPE + 1) / 2)   // 2080 triangular blocks = 32*65
#define SAMPLE 1024        // sampled columns for the kth upper bound
#define CAP 384            // per-row candidate capacity (E[n]~120, P(ovf)~1e-8/row)
#define WQCAP 1024         // per-wave LDS hit queue entries (8KB/wave; expected ~120)

typedef float f32x4 __attribute__((ext_vector_type(4)));
typedef _Float16 f16x8 __attribute__((ext_vector_type(8)));

#define AS1U(p) ((const __attribute__((address_space(1))) unsigned int*)(p))
#define AS3U(p) ((__attribute__((address_space(3))) unsigned int*)(p))

// ---------- helpers: order-preserving float<->uint key ----------
__device__ __forceinline__ unsigned fkey(float f) {
    unsigned u = __float_as_uint(f);
    return (u & 0x80000000u) ? ~u : (u | 0x80000000u);
}
__device__ __forceinline__ float finv(unsigned k) {
    unsigned u = (k & 0x80000000u) ? (k ^ 0x80000000u) : ~k;
    return __uint_as_float(u);
}

// ---------- prep: norms + fp32->fp16 K-panel-major repack + zero out ----------
// Efp layout: [kc][row][64] fp16 (kc = K/64 panel). Within each row's 64-elem
// chunk, 16B units are stored at unit^(row&7) — the T2 bank swizzle baked into
// the layout so linear global_load_lds staging yields conflict-free LDS reads.
__global__ __launch_bounds__(256) void prep_kernel(const float* __restrict__ E,
                                                   unsigned short* __restrict__ Efp,
                                                   float* __restrict__ norms,
                                                   float* __restrict__ out) {
    if (blockIdx.x == 0 && threadIdx.x == 0) out[0] = 0.0f;
    const int wave = threadIdx.x >> 6, lane = threadIdx.x & 63;
    const int row = blockIdx.x * 4 + wave;
    const float4* e4 = (const float4*)(E + (size_t)row * DIM);
    float4 a = e4[lane * 2], b = e4[lane * 2 + 1];      // elems [lane*8, lane*8+8)
    f16x8 h;
    h[0] = (_Float16)a.x; h[1] = (_Float16)a.y; h[2] = (_Float16)a.z; h[3] = (_Float16)a.w;
    h[4] = (_Float16)b.x; h[5] = (_Float16)b.y; h[6] = (_Float16)b.z; h[7] = (_Float16)b.w;
    const int kc = lane >> 3;                            // K-panel 0..7
    const int u  = lane & 7;                             // 16B unit within panel-row
    *(f16x8*)(Efp + ((size_t)kc * N_CELLS + row) * 64 + (size_t)(u ^ (row & 7)) * 8) = h;
    float s = a.x*a.x + a.y*a.y + a.z*a.z + a.w*a.w
            + b.x*b.x + b.y*b.y + b.z*b.z + b.w*b.w;
    #pragma unroll
    for (int off = 32; off > 0; off >>= 1) s += __shfl_down(s, off, 64);
    if (lane == 0) norms[row] = s;
}

// ---------- legacy norms-only (tiny-ws fallback path) ----------
__global__ __launch_bounds__(256) void norms_kernel(const float* __restrict__ E,
                                                    float* __restrict__ norms,
                                                    float* __restrict__ out) {
    if (blockIdx.x == 0 && threadIdx.x == 0) out[0] = 0.0f;
    const int wave = threadIdx.x >> 6, lane = threadIdx.x & 63;
    const int row = blockIdx.x * 4 + wave;
    const float4* e4 = (const float4*)(E + (size_t)row * DIM);
    float4 a = e4[lane], b = e4[lane + 64];
    float s = a.x*a.x + a.y*a.y + a.z*a.z + a.w*a.w
            + b.x*b.x + b.y*b.y + b.z*b.z + b.w*b.w;
    #pragma unroll
    for (int off = 32; off > 0; off >>= 1) s += __shfl_down(s, off, 64);
    if (lane == 0) norms[row] = s;
}

// ====== packed-panel BK=64 GEMM core, 2-iteration jam (R11 proven config) ====
// Staging: fully-contiguous 1KB/wave-instruction reads from Efp panels into
// linear tiles. Buffer pair p at smem + p*32768: A [0,16K), B [16K,32K).
// Per jam-step: stage BOTH buffer pairs (16 loads/thread), ONE barrier+drain,
// then 2x compute back-to-back. Fragment reads XOR the lane-constant
// fx=(fr&7)<<4 to undo the baked swizzle.

#define STAGE_PACKED(BUF, it)                                                                     \
    do {                                                                                          \
        const unsigned short* pa_ = Efp + ((size_t)(it) * N_CELLS + arow) * 64;                   \
        const unsigned short* pb_ = Efp + ((size_t)(it) * N_CELLS + brow) * 64;                   \
        _Pragma("unroll")                                                                         \
        for (int q_ = 0; q_ < 4; q_++) {                                                          \
            __builtin_amdgcn_global_load_lds(AS1U(pa_ + q_*2048 + t*8),                           \
                                             AS3U((BUF) + q_*4096 + t*16), 16, 0, 0);             \
            __builtin_amdgcn_global_load_lds(AS1U(pb_ + q_*2048 + t*8),                           \
                                             AS3U((BUF) + 16384 + q_*4096 + t*16), 16, 0, 0);     \
        }                                                                                         \
    } while (0)

#define GEMM_COMPUTE(BUF)                                                                         \
    do {                                                                                          \
        _Pragma("unroll")                                                                         \
        for (int ks = 0; ks < 2; ks++) {                                                          \
            f16x8 af[4], bf[4];                                                                   \
            _Pragma("unroll")                                                                     \
            for (int tm = 0; tm < 4; tm++)                                                        \
                af[tm] = *(const f16x8*)((BUF) + (size_t)(wr*64 + tm*16 + fr) * 128               \
                                              + (((ks*4 + kg) * 16) ^ fx));                       \
            _Pragma("unroll")                                                                     \
            for (int tn = 0; tn < 4; tn++)                                                        \
                bf[tn] = *(const f16x8*)((BUF) + 16384 + (size_t)(wc*64 + tn*16 + fr) * 128       \
                                              + (((ks*4 + kg) * 16) ^ fx));                       \
            _Pragma("unroll")                                                                     \
            for (int tm = 0; tm < 4; tm++)                                                        \
                _Pragma("unroll")                                                                 \
                for (int tn = 0; tn < 4; tn++)                                                    \
                    acc[tm][tn] = __builtin_amdgcn_mfma_f32_16x16x32_f16(af[tm], bf[tn],          \
                                                                         acc[tm][tn], 0, 0, 0);  \
        }                                                                                         \
    } while (0)

#define GEMM_LOOP()                                                                               \
    do {                                                                                          \
        _Pragma("unroll")                                                                         \
        for (int it2 = 0; it2 < KITERS; it2 += 2) {                                               \
            __syncthreads();                                                                      \
            STAGE_PACKED(smem, it2);                                                              \
            STAGE_PACKED(smem + 32768, it2 + 1);                                                  \
            __syncthreads();                                                                      \
            GEMM_COMPUTE(smem);                                                                   \
            GEMM_COMPUTE(smem + 32768);                                                           \
        }                                                                                         \
        __syncthreads();                                                                          \
    } while (0)

// ---------- sample GEMM: distances for cols [0,SAMPLE), writes Dsamp ----------
// Bitwise-identical MFMA chain to main_cand (same Efp panels, same fragment
// order, same BK sequence) so the sampled 15th is a valid >= bound on the
// full-row 15th; the dot is bitwise symmetric (products commute; k-order
// fixed), so main's triangular orientation reproduces these exact values.
__global__ __launch_bounds__(256) void samp_dist_kernel(const unsigned short* __restrict__ Efp,
                                                        const float* __restrict__ norms,
                                                        float* __restrict__ Dsamp) {
    __shared__ __align__(16) char smem[65536];

    const int t = threadIdx.x;
    const int lane = t & 63;
    const int w = t >> 6;
    const int wr = w >> 1, wc = w & 1;

    const int arow = blockIdx.y * TILE;
    const int brow = blockIdx.x * TILE;     // < SAMPLE

    const int kg = lane >> 4;
    const int fr = lane & 15;
    const int fx = (fr & 7) << 4;

    f32x4 acc[4][4];
    #pragma unroll
    for (int a = 0; a < 4; a++)
        #pragma unroll
        for (int b = 0; b < 4; b++)
            acc[a][b] = (f32x4){0.f, 0.f, 0.f, 0.f};

    GEMM_LOOP();

    const int colb = brow + wc * 64 + fr;
    const int rowb = arow + wr * 64 + (lane >> 4) * 4;
    #pragma unroll
    for (int tn = 0; tn < 4; tn++) {
        const int col = colb + tn * 16;
        const float nj = norms[col];
        #pragma unroll
        for (int tm = 0; tm < 4; tm++) {
            #pragma unroll
            for (int r = 0; r < 4; r++) {
                const int row = rowb + tm * 16 + r;
                float d = norms[row] + nj - 2.0f * acc[tm][tn][r];
                if (row == col) d += 1e10f;
                Dsamp[(size_t)row * SAMPLE + col] = d;
            }
        }
    }
}

// ---------- T-select: exact 15th smallest of each sampled row (1024 elems) ---
// 4 rows per 256-thread block (one row per wave). Sort-free: count-based
// bit search between row min and row max; T[row] >= true full-row 15th.
__global__ __launch_bounds__(256) void tsel_kernel(const float* __restrict__ Dsamp,
                                                   float* __restrict__ T,
                                                   int* __restrict__ cnt) {
    const int row = blockIdx.x * 4 + (threadIdx.x >> 6);
    const int lane = threadIdx.x & 63;
    const float4* r4 = (const float4*)(Dsamp + (size_t)row * SAMPLE);

    float v[16];
    #pragma unroll
    for (int s = 0; s < 4; s++) {
        float4 d4 = r4[s * 64 + lane];
        v[s*4+0] = d4.x; v[s*4+1] = d4.y; v[s*4+2] = d4.z; v[s*4+3] = d4.w;
    }
    float mn = v[0], mx = v[0];
    #pragma unroll
    for (int k = 1; k < 16; k++) { mn = fminf(mn, v[k]); mx = fmaxf(mx, v[k]); }
    #pragma unroll
    for (int off = 32; off > 0; off >>= 1) {
        mn = fminf(mn, __shfl_down(mn, off, 64));
        mx = fmaxf(mx, __shfl_down(mx, off, 64));
    }
    mn = __shfl(mn, 0, 64);
    mx = __shfl(mx, 0, 64);

    unsigned lo = fkey(mn), hi = fkey(mx);   // count(<=mx)=1024 >= 15
    int it = 0;
    while (lo < hi && it < 34) {
        it++;
        const unsigned mid = lo + ((hi - lo) >> 1);
        const float fm = finv(mid);
        int c = 0;
        #pragma unroll
        for (int k = 0; k < 16; k++) c += (v[k] <= fm) ? 1 : 0;
        #pragma unroll
        for (int off = 32; off > 0; off >>= 1) c += __shfl_down(c, off, 64);
        c = __shfl(c, 0, 64);
        if (c >= 15) hi = mid; else lo = mid + 1;
    }
    if (lane == 0) { T[row] = finv(lo); cnt[row] = 0; }
}

// ---------- main GEMM: folded triangular grid (2080 = 32x65), both dirs ------
// Fold: pair row y with row 63-y so every 65 consecutive fids form one
// constant-width epoch touching exactly TWO A-stripes (256 KB, L2-resident)
// while B walks from col 0. fid -> y=fid/65, x=fid%65;
// x<=y ? (a,b)=(y,x) : (a,b)=(63-y,x-y-1).
// Pair (i,j) computed ONCE (dot bitwise symmetric): d serves row i
// (label=labels[j]) AND row j (label=labels[i]). Diagonal tiles gate row>col.
__global__ __launch_bounds__(256) void main_cand_kernel(const unsigned short* __restrict__ Efp,
                                                        const float* __restrict__ norms,
                                                        const int* __restrict__ labels,
                                                        const float* __restrict__ T,
                                                        int* __restrict__ cnt,
                                                        int2* __restrict__ cand) {
    __shared__ __align__(16) char smem[65536];

    const int t = threadIdx.x;
    const int lane = t & 63;
    const int w = t >> 6;
    const int wr = w >> 1, wc = w & 1;

    // folded triangular index -> (a,b), a >= b
    const int fid = blockIdx.x;
    const int y = fid / 65;
    const int x = fid - y * 65;
    const int a = (x <= y) ? y : (NSTRIPE - 1 - y);
    const int b = (x <= y) ? x : (x - y - 1);

    const int arow = a * TILE;               // row stripe (>= col stripe)
    const int brow = b * TILE;               // col stripe
    const bool diag = (a == b);

    const int kg = lane >> 4;
    const int fr = lane & 15;
    const int fx = (fr & 7) << 4;

    f32x4 acc[4][4];
    #pragma unroll
    for (int aa = 0; aa < 4; aa++)
        #pragma unroll
        for (int bb = 0; bb < 4; bb++)
            acc[aa][bb] = (f32x4){0.f, 0.f, 0.f, 0.f};

    GEMM_LOOP();   // trailing __syncthreads: tiles dead -> smem reusable

    // ---- epilogue ----
    int2* wq = (int2*)(smem + (size_t)w * 8192);   // wave-private 1024 entries

    const int colb = brow + wc * 64 + fr;
    const int rowb = arow + wr * 64 + (lane >> 4) * 4;

    // per-thread constants (static indexing -> registers)
    float Trow[4][4], Nrow[4][4];
    int Lrow[4][4];
    #pragma unroll
    for (int tm = 0; tm < 4; tm++)
        #pragma unroll
        for (int r = 0; r < 4; r++) {
            const int row = rowb + tm * 16 + r;
            Trow[tm][r] = T[row];
            Nrow[tm][r] = norms[row];
            Lrow[tm][r] = labels[row];
        }
    float Tcol[4];
    #pragma unroll
    for (int tn = 0; tn < 4; tn++) Tcol[tn] = T[colb + tn * 16];

    int wn = 0;   // wave-uniform queue count
    #pragma unroll
    for (int tn = 0; tn < 4; tn++) {
        const int col = colb + tn * 16;
        const float nj = norms[col];
        const int labc = labels[col];
        #pragma unroll
        for (int tm = 0; tm < 4; tm++) {
            #pragma unroll
            for (int r = 0; r < 4; r++) {
                const int row = rowb + tm * 16 + r;
                const float d = Nrow[tm][r] + nj - 2.0f * acc[tm][tn][r];
                const bool live = !diag || (row > col);   // excludes row==col
                // direction A: candidate for row `row`, label = labels[col]
                {
                    const bool hit = live && (d <= Trow[tm][r]);
                    const unsigned long long bal = __ballot(hit);
                    if (hit) {
                        const int pos = __popcll(bal & ((1ull << lane) - 1ull));
                        if (wn + pos < WQCAP)
                            wq[wn + pos] = make_int2(__float_as_int(d), row | (labc << 13));
                    }
                    wn += (int)__popcll(bal);
                }
                // direction B: candidate for row `col`, label = labels[row]
                {
                    const bool hit = live && (d <= Tcol[tn]);
                    const unsigned long long bal = __ballot(hit);
                    if (hit) {
                        const int pos = __popcll(bal & ((1ull << lane) - 1ull));
                        if (wn + pos < WQCAP)
                            wq[wn + pos] = make_int2(__float_as_int(d), col | (Lrow[tm][r] << 13));
                    }
                    wn += (int)__popcll(bal);
                }
            }
        }
    }

    // flush own segment (independent per-thread global atomics)
    const int qn = (wn < WQCAP) ? wn : WQCAP;
    for (int i = lane; i < qn; i += 64) {
        const int2 e = wq[i];
        const int row = e.y & 8191;
        const int lab = e.y >> 13;
        const int idx = atomicAdd(&cnt[row], 1);
        if (idx < CAP) cand[(size_t)row * CAP + idx] = make_int2(e.x, lab);
    }
    // overflow (never expected): poison both stripes -> exact fallback
    if (wn > WQCAP)
        for (int r2 = lane; r2 < TILE; r2 += 64) {
            atomicAdd(&cnt[arow + r2], 1000000);
            atomicAdd(&cnt[brow + r2], 1000000);
        }
}

// ---------- finalize: exact kth + truncated sums; PLAIN STORE to rowloss -----
// 4 rows per 256-thread block (one per wave). No same-address atomics, no
// fences. Truncation error <= 8192*exp(-(T-dmin)) ~ e^-40 — below fp32 ulp.
__global__ __launch_bounds__(256) void final_kernel(const int2* __restrict__ cand,
                                                    const int* __restrict__ cnt,
                                                    const float* __restrict__ T,
                                                    float* __restrict__ rowloss) {
    const int row = blockIdx.x * 4 + (threadIdx.x >> 6);
    const int lane = threadIdx.x & 63;
    const int n = cnt[row];
    if (n < 15 || n > CAP) return;          // overflow rows: fused fallback writes

    float d[CAP / 64];
    int lb[CAP / 64];
    #pragma unroll
    for (int s = 0; s < CAP / 64; s++) {
        const int idx = s * 64 + lane;
        if (idx < n) {
            const int2 c = cand[(size_t)row * CAP + idx];
            d[s] = __int_as_float(c.x);
            lb[s] = c.y;
        } else { d[s] = 3.0e38f; lb[s] = 3; }
    }

    float dmin = d[0];
    #pragma unroll
    for (int s = 1; s < CAP / 64; s++) dmin = fminf(dmin, d[s]);
    #pragma unroll
    for (int off = 32; off > 0; off >>= 1) dmin = fminf(dmin, __shfl_down(dmin, off, 64));
    dmin = __shfl(dmin, 0, 64);

    unsigned lo = fkey(dmin), hi = fkey(T[row]);   // count(<=T) = n >= 15
    int it = 0;
    while (lo < hi && it < 34) {
        it++;
        const unsigned mid = lo + ((hi - lo) >> 1);
        const float fm = finv(mid);
        int c = 0;
        #pragma unroll
        for (int s = 0; s < CAP / 64; s++) c += (d[s] <= fm) ? 1 : 0;
        #pragma unroll
        for (int off = 32; off > 0; off >>= 1) c += __shfl_down(c, off, 64);
        c = __shfl(c, 0, 64);
        if (c >= 15) hi = mid; else lo = mid + 1;
    }
    const float kth = finv(lo);

    float z = 0.f, s0 = 0.f, s1 = 0.f, s2 = 0.f;
    #pragma unroll
    for (int s = 0; s < CAP / 64; s++) {
        const float w = __expf(dmin - d[s]);              // sentinel -> 0
        const float msk = 1.0f / (1.0f + __expf(d[s] - kth));
        const float p = w * msk;
        z  += w;
        s0 += (lb[s] == 0) ? p : 0.f;
        s1 += (lb[s] == 1) ? p : 0.f;
        s2 += (lb[s] == 2) ? p : 0.f;
    }
    #pragma unroll
    for (int off = 32; off > 0; off >>= 1) {
        z  += __shfl_down(z,  off, 64);
        s0 += __shfl_down(s0, off, 64);
        s1 += __shfl_down(s1, off, 64);
        s2 += __shfl_down(s2, off, 64);
    }
    if (lane == 0) {
        const float ssum = s0 + s1 + s2;
        const float denom = ssum + 1e-8f * z;
        const float q0 = s0/denom, q1 = s1/denom, q2 = s2/denom;
        const float H = -(q0*logf(q0+1e-8f) + q1*logf(q1+1e-8f) + q2*logf(q2+1e-8f));
        rowloss[row] = -(H / (logf(3.0f) + 1e-8f)) * (1.0f / N_CELLS);
    }
}

// ---------- reduce: sum rowloss -> out (single block, no atomics) ----------
__global__ __launch_bounds__(512) void reduce_kernel(const float* __restrict__ rowloss,
                                                     float* __restrict__ out) {
    __shared__ float wsum[8];
    const int t = threadIdx.x, lane = t & 63, wv = t >> 6;
    const float4* r4 = (const float4*)rowloss;
    float s = 0.f;
    for (int i = t; i < N_CELLS / 4; i += 512) {
        const float4 v = r4[i];
        s += v.x + v.y + v.z + v.w;
    }
    #pragma unroll
    for (int off = 32; off > 0; off >>= 1) s += __shfl_down(s, off, 64);
    if (lane == 0) wsum[wv] = s;
    __syncthreads();
    if (t == 0) {
        float tot = 0.f;
        #pragma unroll
        for (int i = 0; i < 8; i++) tot += wsum[i];
        out[0] = tot;
    }
}

// ---------- shared tail for fused fallback ----------
// rowloss != nullptr: store per-row contrib (main path insurance).
// rowloss == nullptr: atomicAdd to out (tiny-ws full mode).
template<int NT>
__device__ __forceinline__ void finish_row(const float* rowb,
                                           float lst[15],
                                           const int* __restrict__ labels,
                                           float* __restrict__ out,
                                           float* __restrict__ rowloss,
                                           int rowidx) {
    constexpr int WAVES = NT / 64;
    __shared__ float w0s[WAVES], w14s[WAVES];
    __shared__ int cnt;
    __shared__ float zz[WAVES], r0s[WAVES], r1s[WAVES], r2s[WAVES];

    const int t = threadIdx.x;
    const int lane = t & 63, wave = t >> 6;

    float m0 = lst[0], m14 = lst[14];
    #pragma unroll
    for (int off = 32; off > 0; off >>= 1) {
        m0  = fminf(m0,  __shfl_down(m0,  off, 64));
        m14 = fminf(m14, __shfl_down(m14, off, 64));
    }
    if (lane == 0) { w0s[wave] = m0; w14s[wave] = m14; }
    __syncthreads();
    float dmin = w0s[0], ub = w14s[0];
    #pragma unroll
    for (int i = 1; i < WAVES; i++) { dmin = fminf(dmin, w0s[i]); ub = fminf(ub, w14s[i]); }

    unsigned lo = fkey(dmin), hi = fkey(ub);
    int iter = 0;
    while (lo < hi && iter < 34) {
        iter++;
        const unsigned mid = lo + ((hi - lo) >> 1);
        const float fmid = finv(mid);
        int c = 0;
        #pragma unroll
        for (int k = 0; k < 15; k++) c += (lst[k] <= fmid) ? 1 : 0;
        #pragma unroll
        for (int off = 32; off > 0; off >>= 1) c += __shfl_down(c, off, 64);
        __syncthreads();
        if (t == 0) cnt = 0;
        __syncthreads();
        if (lane == 0) atomicAdd(&cnt, c);
        __syncthreads();
        const int total = cnt;
        if (total >= 15) hi = mid; else lo = mid + 1;
    }
    const float kth = finv(hi);

    const float4* rb4 = (const float4*)rowb;
    const int4* lb4 = (const int4*)labels;
    float z = 0.f, s0 = 0.f, s1 = 0.f, s2 = 0.f;
    #pragma unroll
    for (int s = 0; s < N_CELLS / (4 * NT); s++) {
        const int idx = s * NT + t;
        const float4 d4 = rb4[idx];
        const int4 l4 = lb4[idx];
        #pragma unroll
        for (int c2 = 0; c2 < 4; c2++) {
            const float d = (c2 == 0) ? d4.x : (c2 == 1) ? d4.y : (c2 == 2) ? d4.z : d4.w;
            const int lab = (c2 == 0) ? l4.x : (c2 == 1) ? l4.y : (c2 == 2) ? l4.z : l4.w;
            const float w = __expf(dmin - d);
            const float msk = 1.0f / (1.0f + __expf(d - kth));
            const float p = w * msk;
            z  += w;
            s0 += (lab == 0) ? p : 0.f;
            s1 += (lab == 1) ? p : 0.f;
            s2 += (lab == 2) ? p : 0.f;
        }
    }
    #pragma unroll
    for (int off = 32; off > 0; off >>= 1) {
        z  += __shfl_down(z,  off, 64);
        s0 += __shfl_down(s0, off, 64);
        s1 += __shfl_down(s1, off, 64);
        s2 += __shfl_down(s2, off, 64);
    }
    if (lane == 0) { zz[wave] = z; r0s[wave] = s0; r1s[wave] = s1; r2s[wave] = s2; }
    __syncthreads();
    if (t == 0) {
        float Z = 0.f, S0 = 0.f, S1 = 0.f, S2 = 0.f;
        #pragma unroll
        for (int i = 0; i < WAVES; i++) { Z += zz[i]; S0 += r0s[i]; S1 += r1s[i]; S2 += r2s[i]; }
        const float ssum = S0 + S1 + S2;
        const float denom = ssum + 1e-8f * Z;
        const float q0 = S0/denom, q1 = S1/denom, q2 = S2/denom;
        const float H = -(q0*logf(q0+1e-8f) + q1*logf(q1+1e-8f) + q2*logf(q2+1e-8f));
        const float contrib = -(H / (logf(3.0f) + 1e-8f)) * (1.0f / N_CELLS);
        if (rowloss) rowloss[rowidx] = contrib;
        else atomicAdd(out, contrib);
    }
}

// ---------- fused fp32 full-row recompute (exact) ----------
__device__ void process_row(int i,
                            const float* __restrict__ E,
                            const float* __restrict__ norms,
                            const int* __restrict__ labels,
                            float* __restrict__ out,
                            float* __restrict__ rowloss,
                            float* rowb, float* ei) {
    const int t = threadIdx.x;
    __syncthreads();
    for (int k = t; k < DIM; k += 512) ei[k] = E[(size_t)i * DIM + k];
    __syncthreads();
    const float ni = norms[i];

    float lst[15];
    #pragma unroll
    for (int k = 0; k < 15; k++) lst[k] = 3.0e38f;

    for (int s = 0; s < N_CELLS / 512; s++) {
        const int j = s * 512 + t;
        const float* ej = E + (size_t)j * DIM;
        float dot = 0.f;
        #pragma unroll 4
        for (int k = 0; k < DIM; k += 4) {
            float4 e4 = *(const float4*)(ej + k);
            dot += ei[k]*e4.x + ei[k+1]*e4.y + ei[k+2]*e4.z + ei[k+3]*e4.w;
        }
        float d = ni + norms[j] - 2.0f * dot;
        if (j == i) d += 1e10f;
        rowb[j] = d;
        float v = d;
        #pragma unroll
        for (int k = 0; k < 15; k++) {
            float lo2 = fminf(lst[k], v);
            v = fmaxf(lst[k], v);
            lst[k] = lo2;
        }
    }
    finish_row<512>(rowb, lst, labels, out, rowloss, i);
}

// cnt_g == nullptr: tiny-ws full mode (grid N_CELLS, one row per block,
// atomic accumulate to out). cnt_g != nullptr: insurance mode (grid 64):
// scan 128 rows each, process only failed rows (~never), store to rowloss.
__global__ __launch_bounds__(512) void fused_kernel(const float* __restrict__ E,
                                                    const float* __restrict__ norms,
                                                    const int* __restrict__ labels,
                                                    float* __restrict__ out,
                                                    float* __restrict__ rowloss,
                                                    const int* __restrict__ cnt_g) {
    __shared__ float rowb[N_CELLS];
    __shared__ float ei[DIM];
    __shared__ int bad[TILE];
    __shared__ int nbad;
    const int t = threadIdx.x;

    if (cnt_g == nullptr) {
        process_row(blockIdx.x, E, norms, labels, out, nullptr, rowb, ei);
        return;
    }
    if (t == 0) nbad = 0;
    __syncthreads();
    if (t < TILE) {
        const int row = blockIdx.x * TILE + t;
        const int n = cnt_g[row];
        if (n < 15 || n > CAP) bad[atomicAdd(&nbad, 1)] = row;
    }
    __syncthreads();
    const int nb = nbad;
    for (int b = 0; b < nb; b++)
        process_row(bad[b], E, norms, labels, out, rowloss, rowb, ei);
}

// ---------- launcher ----------
// ws: norms 32KB | Efp fp16 8MB | T 32KB | cnt 32KB | rowloss 32KB
//     | Dsamp 32MB | cand 25MB
extern "C" void kernel_launch(void* const* d_in, const int* in_sizes, int n_in,
                              void* d_out, int out_size, void* d_ws, size_t ws_size,
                              hipStream_t stream) {
    const float* E = (const float*)d_in[0];
    const int* labels = (const int*)d_in[1];
    float* out = (float*)d_out;

    char* p = (char*)d_ws;
    float* norms = (float*)p;                 p += 32768;
    unsigned short* Efp = (unsigned short*)p; p += (size_t)N_CELLS * DIM * 2;
    float* T = (float*)p;                     p += 32768;
    int* cnt = (int*)p;                       p += 32768;
    float* rowloss = (float*)p;               p += 32768;
    float* Dsamp = (float*)p;                 p += (size_t)N_CELLS * SAMPLE * 4;
    int2* cand = (int2*)p;                    p += (size_t)N_CELLS * CAP * 8;
    const size_t need = (size_t)(p - (char*)d_ws);

    if (ws_size >= need) {
        prep_kernel<<<N_CELLS / 4, 256, 0, stream>>>(E, Efp, norms, out);
        samp_dist_kernel<<<dim3(SAMPLE / TILE, N_CELLS / TILE), 256, 0, stream>>>(Efp, norms, Dsamp);
        tsel_kernel<<<N_CELLS / 4, 256, 0, stream>>>(Dsamp, T, cnt);
        main_cand_kernel<<<NTRI, 256, 0, stream>>>(Efp, norms, labels, T, cnt, cand);
        final_kernel<<<N_CELLS / 4, 256, 0, stream>>>(cand, cnt, T, rowloss);
        fused_kernel<<<N_CELLS / TILE, 512, 0, stream>>>(E, norms, labels, out, rowloss, cnt);  // insurance
        reduce_kernel<<<1, 512, 0, stream>>>(rowloss, out);
    } else {
        norms_kernel<<<N_CELLS / 4, 256, 0, stream>>>(E, norms, out);
        fused_kernel<<<N_CELLS, 512, 0, stream>>>(E, norms, labels, out, nullptr, nullptr);
    }
}

// Round 17
// 249.766 us; speedup vs baseline: 1.4793x; 1.0204x over previous
//
#include <hip/hip_runtime.h>
#include <math.h>

#define N_CELLS 8192
#define DIM 512
#define TILE 128
#define BK 64
#define KITERS (DIM / BK)
#define NSTRIPE (N_CELLS / TILE)             // 64 stripes
#define NTRI (NSTRIPE * (NSTRIPE + 1) / 2)   // 2080 triangular blocks = 32*65
#define SAMPLE 1024        // sampled columns for the kth upper bound
#define CAP 384            // per-row candidate capacity (E[n]~120, P(ovf)~1e-8/row)
#define WQCAP 1024         // per-wave LDS hit queue entries (8KB/wave; expected ~120)

typedef float f32x4 __attribute__((ext_vector_type(4)));
typedef _Float16 f16x8 __attribute__((ext_vector_type(8)));

#define AS1U(p) ((const __attribute__((address_space(1))) unsigned int*)(p))
#define AS3U(p) ((__attribute__((address_space(3))) unsigned int*)(p))

// ---------- helpers: order-preserving float<->uint key ----------
__device__ __forceinline__ unsigned fkey(float f) {
    unsigned u = __float_as_uint(f);
    return (u & 0x80000000u) ? ~u : (u | 0x80000000u);
}
__device__ __forceinline__ float finv(unsigned k) {
    unsigned u = (k & 0x80000000u) ? (k ^ 0x80000000u) : ~k;
    return __uint_as_float(u);
}

// ---------- prep: norms + fp32->fp16 K-panel-major repack + zero out ----------
// Efp layout: [kc][row][64] fp16 (kc = K/64 panel). Within each row's 64-elem
// chunk, 16B units are stored at unit^(row&7) — the T2 bank swizzle baked into
// the layout so linear global_load_lds staging yields conflict-free LDS reads.
__global__ __launch_bounds__(256) void prep_kernel(const float* __restrict__ E,
                                                   unsigned short* __restrict__ Efp,
                                                   float* __restrict__ norms,
                                                   float* __restrict__ out) {
    if (blockIdx.x == 0 && threadIdx.x == 0) out[0] = 0.0f;
    const int wave = threadIdx.x >> 6, lane = threadIdx.x & 63;
    const int row = blockIdx.x * 4 + wave;
    const float4* e4 = (const float4*)(E + (size_t)row * DIM);
    float4 a = e4[lane * 2], b = e4[lane * 2 + 1];      // elems [lane*8, lane*8+8)
    f16x8 h;
    h[0] = (_Float16)a.x; h[1] = (_Float16)a.y; h[2] = (_Float16)a.z; h[3] = (_Float16)a.w;
    h[4] = (_Float16)b.x; h[5] = (_Float16)b.y; h[6] = (_Float16)b.z; h[7] = (_Float16)b.w;
    const int kc = lane >> 3;                            // K-panel 0..7
    const int u  = lane & 7;                             // 16B unit within panel-row
    *(f16x8*)(Efp + ((size_t)kc * N_CELLS + row) * 64 + (size_t)(u ^ (row & 7)) * 8) = h;
    float s = a.x*a.x + a.y*a.y + a.z*a.z + a.w*a.w
            + b.x*b.x + b.y*b.y + b.z*b.z + b.w*b.w;
    #pragma unroll
    for (int off = 32; off > 0; off >>= 1) s += __shfl_down(s, off, 64);
    if (lane == 0) norms[row] = s;
}

// ---------- legacy norms-only (tiny-ws fallback path) ----------
__global__ __launch_bounds__(256) void norms_kernel(const float* __restrict__ E,
                                                    float* __restrict__ norms,
                                                    float* __restrict__ out) {
    if (blockIdx.x == 0 && threadIdx.x == 0) out[0] = 0.0f;
    const int wave = threadIdx.x >> 6, lane = threadIdx.x & 63;
    const int row = blockIdx.x * 4 + wave;
    const float4* e4 = (const float4*)(E + (size_t)row * DIM);
    float4 a = e4[lane], b = e4[lane + 64];
    float s = a.x*a.x + a.y*a.y + a.z*a.z + a.w*a.w
            + b.x*b.x + b.y*b.y + b.z*b.z + b.w*b.w;
    #pragma unroll
    for (int off = 32; off > 0; off >>= 1) s += __shfl_down(s, off, 64);
    if (lane == 0) norms[row] = s;
}

// ====== packed-panel BK=64 GEMM core, 2-iteration jam (R11 proven config) ====
// Staging: fully-contiguous 1KB/wave-instruction reads from Efp panels into
// linear tiles. Buffer pair p at smem + p*32768: A [0,16K), B [16K,32K).
// Per jam-step: stage BOTH buffer pairs (16 loads/thread), ONE barrier+drain,
// then 2x compute back-to-back. Fragment reads XOR the lane-constant
// fx=(fr&7)<<4 to undo the baked swizzle.

#define STAGE_PACKED(BUF, it)                                                                     \
    do {                                                                                          \
        const unsigned short* pa_ = Efp + ((size_t)(it) * N_CELLS + arow) * 64;                   \
        const unsigned short* pb_ = Efp + ((size_t)(it) * N_CELLS + brow) * 64;                   \
        _Pragma("unroll")                                                                         \
        for (int q_ = 0; q_ < 4; q_++) {                                                          \
            __builtin_amdgcn_global_load_lds(AS1U(pa_ + q_*2048 + t*8),                           \
                                             AS3U((BUF) + q_*4096 + t*16), 16, 0, 0);             \
            __builtin_amdgcn_global_load_lds(AS1U(pb_ + q_*2048 + t*8),                           \
                                             AS3U((BUF) + 16384 + q_*4096 + t*16), 16, 0, 0);     \
        }                                                                                         \
    } while (0)

#define GEMM_COMPUTE(BUF)                                                                         \
    do {                                                                                          \
        _Pragma("unroll")                                                                         \
        for (int ks = 0; ks < 2; ks++) {                                                          \
            f16x8 af[4], bf[4];                                                                   \
            _Pragma("unroll")                                                                     \
            for (int tm = 0; tm < 4; tm++)                                                        \
                af[tm] = *(const f16x8*)((BUF) + (size_t)(wr*64 + tm*16 + fr) * 128               \
                                              + (((ks*4 + kg) * 16) ^ fx));                       \
            _Pragma("unroll")                                                                     \
            for (int tn = 0; tn < 4; tn++)                                                        \
                bf[tn] = *(const f16x8*)((BUF) + 16384 + (size_t)(wc*64 + tn*16 + fr) * 128       \
                                              + (((ks*4 + kg) * 16) ^ fx));                       \
            _Pragma("unroll")                                                                     \
            for (int tm = 0; tm < 4; tm++)                                                        \
                _Pragma("unroll")                                                                 \
                for (int tn = 0; tn < 4; tn++)                                                    \
                    acc[tm][tn] = __builtin_amdgcn_mfma_f32_16x16x32_f16(af[tm], bf[tn],          \
                                                                         acc[tm][tn], 0, 0, 0);  \
        }                                                                                         \
    } while (0)

#define GEMM_LOOP()                                                                               \
    do {                                                                                          \
        _Pragma("unroll")                                                                         \
        for (int it2 = 0; it2 < KITERS; it2 += 2) {                                               \
            __syncthreads();                                                                      \
            STAGE_PACKED(smem, it2);                                                              \
            STAGE_PACKED(smem + 32768, it2 + 1);                                                  \
            __syncthreads();                                                                      \
            GEMM_COMPUTE(smem);                                                                   \
            GEMM_COMPUTE(smem + 32768);                                                           \
        }                                                                                         \
        __syncthreads();                                                                          \
    } while (0)

// ---------- sample GEMM: distances for cols [0,SAMPLE), writes Dsamp ----------
// Bitwise-identical MFMA chain to main_cand (same Efp panels, same fragment
// order, same BK sequence) so the sampled 15th is a valid >= bound on the
// full-row 15th; the dot is bitwise symmetric (products commute; k-order
// fixed), so main's triangular orientation reproduces these exact values.
__global__ __launch_bounds__(256) void samp_dist_kernel(const unsigned short* __restrict__ Efp,
                                                        const float* __restrict__ norms,
                                                        float* __restrict__ Dsamp) {
    __shared__ __align__(16) char smem[65536];

    const int t = threadIdx.x;
    const int lane = t & 63;
    const int w = t >> 6;
    const int wr = w >> 1, wc = w & 1;

    const int arow = blockIdx.y * TILE;
    const int brow = blockIdx.x * TILE;     // < SAMPLE

    const int kg = lane >> 4;
    const int fr = lane & 15;
    const int fx = (fr & 7) << 4;

    f32x4 acc[4][4];
    #pragma unroll
    for (int a = 0; a < 4; a++)
        #pragma unroll
        for (int b = 0; b < 4; b++)
            acc[a][b] = (f32x4){0.f, 0.f, 0.f, 0.f};

    GEMM_LOOP();

    const int colb = brow + wc * 64 + fr;
    const int rowb = arow + wr * 64 + (lane >> 4) * 4;
    #pragma unroll
    for (int tn = 0; tn < 4; tn++) {
        const int col = colb + tn * 16;
        const float nj = norms[col];
        #pragma unroll
        for (int tm = 0; tm < 4; tm++) {
            #pragma unroll
            for (int r = 0; r < 4; r++) {
                const int row = rowb + tm * 16 + r;
                float d = norms[row] + nj - 2.0f * acc[tm][tn][r];
                if (row == col) d += 1e10f;
                Dsamp[(size_t)row * SAMPLE + col] = d;
            }
        }
    }
}

// ---------- T-select: exact 15th smallest of each sampled row (1024 elems) ---
// 4 rows per 256-thread block (one row per wave). Sort-free: count-based
// bit search between row min and row max; T[row] >= true full-row 15th.
__global__ __launch_bounds__(256) void tsel_kernel(const float* __restrict__ Dsamp,
                                                   float* __restrict__ T,
                                                   int* __restrict__ cnt) {
    const int row = blockIdx.x * 4 + (threadIdx.x >> 6);
    const int lane = threadIdx.x & 63;
    const float4* r4 = (const float4*)(Dsamp + (size_t)row * SAMPLE);

    float v[16];
    #pragma unroll
    for (int s = 0; s < 4; s++) {
        float4 d4 = r4[s * 64 + lane];
        v[s*4+0] = d4.x; v[s*4+1] = d4.y; v[s*4+2] = d4.z; v[s*4+3] = d4.w;
    }
    float mn = v[0], mx = v[0];
    #pragma unroll
    for (int k = 1; k < 16; k++) { mn = fminf(mn, v[k]); mx = fmaxf(mx, v[k]); }
    #pragma unroll
    for (int off = 32; off > 0; off >>= 1) {
        mn = fminf(mn, __shfl_down(mn, off, 64));
        mx = fmaxf(mx, __shfl_down(mx, off, 64));
    }
    mn = __shfl(mn, 0, 64);
    mx = __shfl(mx, 0, 64);

    unsigned lo = fkey(mn), hi = fkey(mx);   // count(<=mx)=1024 >= 15
    int it = 0;
    while (lo < hi && it < 34) {
        it++;
        const unsigned mid = lo + ((hi - lo) >> 1);
        const float fm = finv(mid);
        int c = 0;
        #pragma unroll
        for (int k = 0; k < 16; k++) c += (v[k] <= fm) ? 1 : 0;
        #pragma unroll
        for (int off = 32; off > 0; off >>= 1) c += __shfl_down(c, off, 64);
        c = __shfl(c, 0, 64);
        if (c >= 15) hi = mid; else lo = mid + 1;
    }
    if (lane == 0) { T[row] = finv(lo); cnt[row] = 0; }
}

// ---------- main GEMM: folded triangular grid (2080 = 32x65), both dirs ------
// Fold: pair row y with row 63-y so every 65 consecutive fids form one
// constant-width epoch touching exactly TWO A-stripes (256 KB, L2-resident)
// while B walks the columns. SERPENTINE: odd epochs reverse the walk
// (x -> 64-x) so consecutive epochs share their boundary B-range -> the
// in-flight window (~2 blocks/CU spans epoch boundaries) gets L2 hits
// instead of re-fetching. fid -> y=fid/65, x=fid%65 (reversed if y odd);
// x<=y ? (a,b)=(y,x) : (a,b)=(63-y,x-y-1).
// Pair (i,j) computed ONCE (dot bitwise symmetric): d serves row i
// (label=labels[j]) AND row j (label=labels[i]). Diagonal tiles gate row>col.
__global__ __launch_bounds__(256) void main_cand_kernel(const unsigned short* __restrict__ Efp,
                                                        const float* __restrict__ norms,
                                                        const int* __restrict__ labels,
                                                        const float* __restrict__ T,
                                                        int* __restrict__ cnt,
                                                        int2* __restrict__ cand) {
    __shared__ __align__(16) char smem[65536];

    const int t = threadIdx.x;
    const int lane = t & 63;
    const int w = t >> 6;
    const int wr = w >> 1, wc = w & 1;

    // folded triangular index -> (a,b), a >= b; serpentine on odd epochs
    const int fid = blockIdx.x;
    const int y = fid / 65;
    int x = fid - y * 65;
    if (y & 1) x = 64 - x;
    const int a = (x <= y) ? y : (NSTRIPE - 1 - y);
    const int b = (x <= y) ? x : (x - y - 1);

    const int arow = a * TILE;               // row stripe (>= col stripe)
    const int brow = b * TILE;               // col stripe
    const bool diag = (a == b);

    const int kg = lane >> 4;
    const int fr = lane & 15;
    const int fx = (fr & 7) << 4;

    f32x4 acc[4][4];
    #pragma unroll
    for (int aa = 0; aa < 4; aa++)
        #pragma unroll
        for (int bb = 0; bb < 4; bb++)
            acc[aa][bb] = (f32x4){0.f, 0.f, 0.f, 0.f};

    GEMM_LOOP();   // trailing __syncthreads: tiles dead -> smem reusable

    // ---- epilogue ----
    int2* wq = (int2*)(smem + (size_t)w * 8192);   // wave-private 1024 entries

    const int colb = brow + wc * 64 + fr;
    const int rowb = arow + wr * 64 + (lane >> 4) * 4;

    // per-thread constants (static indexing -> registers)
    float Trow[4][4], Nrow[4][4];
    int Lrow[4][4];
    #pragma unroll
    for (int tm = 0; tm < 4; tm++)
        #pragma unroll
        for (int r = 0; r < 4; r++) {
            const int row = rowb + tm * 16 + r;
            Trow[tm][r] = T[row];
            Nrow[tm][r] = norms[row];
            Lrow[tm][r] = labels[row];
        }
    float Tcol[4];
    #pragma unroll
    for (int tn = 0; tn < 4; tn++) Tcol[tn] = T[colb + tn * 16];

    int wn = 0;   // wave-uniform queue count
    #pragma unroll
    for (int tn = 0; tn < 4; tn++) {
        const int col = colb + tn * 16;
        const float nj = norms[col];
        const int labc = labels[col];
        #pragma unroll
        for (int tm = 0; tm < 4; tm++) {
            #pragma unroll
            for (int r = 0; r < 4; r++) {
                const int row = rowb + tm * 16 + r;
                const float d = Nrow[tm][r] + nj - 2.0f * acc[tm][tn][r];
                const bool live = !diag || (row > col);   // excludes row==col
                // direction A: candidate for row `row`, label = labels[col]
                {
                    const bool hit = live && (d <= Trow[tm][r]);
                    const unsigned long long bal = __ballot(hit);
                    if (hit) {
                        const int pos = __popcll(bal & ((1ull << lane) - 1ull));
                        if (wn + pos < WQCAP)
                            wq[wn + pos] = make_int2(__float_as_int(d), row | (labc << 13));
                    }
                    wn += (int)__popcll(bal);
                }
                // direction B: candidate for row `col`, label = labels[row]
                {
                    const bool hit = live && (d <= Tcol[tn]);
                    const unsigned long long bal = __ballot(hit);
                    if (hit) {
                        const int pos = __popcll(bal & ((1ull << lane) - 1ull));
                        if (wn + pos < WQCAP)
                            wq[wn + pos] = make_int2(__float_as_int(d), col | (Lrow[tm][r] << 13));
                    }
                    wn += (int)__popcll(bal);
                }
            }
        }
    }

    // flush own segment (independent per-thread global atomics)
    const int qn = (wn < WQCAP) ? wn : WQCAP;
    for (int i = lane; i < qn; i += 64) {
        const int2 e = wq[i];
        const int row = e.y & 8191;
        const int lab = e.y >> 13;
        const int idx = atomicAdd(&cnt[row], 1);
        if (idx < CAP) cand[(size_t)row * CAP + idx] = make_int2(e.x, lab);
    }
    // overflow (never expected): poison both stripes -> exact fallback
    if (wn > WQCAP)
        for (int r2 = lane; r2 < TILE; r2 += 64) {
            atomicAdd(&cnt[arow + r2], 1000000);
            atomicAdd(&cnt[brow + r2], 1000000);
        }
}

// ---------- finalize: exact kth + truncated sums; PLAIN STORE to rowloss -----
// 4 rows per 256-thread block (one per wave). No same-address atomics, no
// fences. Truncation error <= 8192*exp(-(T-dmin)) ~ e^-40 — below fp32 ulp.
__global__ __launch_bounds__(256) void final_kernel(const int2* __restrict__ cand,
                                                    const int* __restrict__ cnt,
                                                    const float* __restrict__ T,
                                                    float* __restrict__ rowloss) {
    const int row = blockIdx.x * 4 + (threadIdx.x >> 6);
    const int lane = threadIdx.x & 63;
    const int n = cnt[row];
    if (n < 15 || n > CAP) return;          // overflow rows: fused fallback writes

    float d[CAP / 64];
    int lb[CAP / 64];
    #pragma unroll
    for (int s = 0; s < CAP / 64; s++) {
        const int idx = s * 64 + lane;
        if (idx < n) {
            const int2 c = cand[(size_t)row * CAP + idx];
            d[s] = __int_as_float(c.x);
            lb[s] = c.y;
        } else { d[s] = 3.0e38f; lb[s] = 3; }
    }

    float dmin = d[0];
    #pragma unroll
    for (int s = 1; s < CAP / 64; s++) dmin = fminf(dmin, d[s]);
    #pragma unroll
    for (int off = 32; off > 0; off >>= 1) dmin = fminf(dmin, __shfl_down(dmin, off, 64));
    dmin = __shfl(dmin, 0, 64);

    unsigned lo = fkey(dmin), hi = fkey(T[row]);   // count(<=T) = n >= 15
    int it = 0;
    while (lo < hi && it < 34) {
        it++;
        const unsigned mid = lo + ((hi - lo) >> 1);
        const float fm = finv(mid);
        int c = 0;
        #pragma unroll
        for (int s = 0; s < CAP / 64; s++) c += (d[s] <= fm) ? 1 : 0;
        #pragma unroll
        for (int off = 32; off > 0; off >>= 1) c += __shfl_down(c, off, 64);
        c = __shfl(c, 0, 64);
        if (c >= 15) hi = mid; else lo = mid + 1;
    }
    const float kth = finv(lo);

    float z = 0.f, s0 = 0.f, s1 = 0.f, s2 = 0.f;
    #pragma unroll
    for (int s = 0; s < CAP / 64; s++) {
        const float w = __expf(dmin - d[s]);              // sentinel -> 0
        const float msk = 1.0f / (1.0f + __expf(d[s] - kth));
        const float p = w * msk;
        z  += w;
        s0 += (lb[s] == 0) ? p : 0.f;
        s1 += (lb[s] == 1) ? p : 0.f;
        s2 += (lb[s] == 2) ? p : 0.f;
    }
    #pragma unroll
    for (int off = 32; off > 0; off >>= 1) {
        z  += __shfl_down(z,  off, 64);
        s0 += __shfl_down(s0, off, 64);
        s1 += __shfl_down(s1, off, 64);
        s2 += __shfl_down(s2, off, 64);
    }
    if (lane == 0) {
        const float ssum = s0 + s1 + s2;
        const float denom = ssum + 1e-8f * z;
        const float q0 = s0/denom, q1 = s1/denom, q2 = s2/denom;
        const float H = -(q0*logf(q0+1e-8f) + q1*logf(q1+1e-8f) + q2*logf(q2+1e-8f));
        rowloss[row] = -(H / (logf(3.0f) + 1e-8f)) * (1.0f / N_CELLS);
    }
}

// ---------- reduce: sum rowloss -> out (single block, no atomics) ----------
__global__ __launch_bounds__(512) void reduce_kernel(const float* __restrict__ rowloss,
                                                     float* __restrict__ out) {
    __shared__ float wsum[8];
    const int t = threadIdx.x, lane = t & 63, wv = t >> 6;
    const float4* r4 = (const float4*)rowloss;
    float s = 0.f;
    for (int i = t; i < N_CELLS / 4; i += 512) {
        const float4 v = r4[i];
        s += v.x + v.y + v.z + v.w;
    }
    #pragma unroll
    for (int off = 32; off > 0; off >>= 1) s += __shfl_down(s, off, 64);
    if (lane == 0) wsum[wv] = s;
    __syncthreads();
    if (t == 0) {
        float tot = 0.f;
        #pragma unroll
        for (int i = 0; i < 8; i++) tot += wsum[i];
        out[0] = tot;
    }
}

// ---------- shared tail for fused fallback ----------
// rowloss != nullptr: store per-row contrib (main path insurance).
// rowloss == nullptr: atomicAdd to out (tiny-ws full mode).
template<int NT>
__device__ __forceinline__ void finish_row(const float* rowb,
                                           float lst[15],
                                           const int* __restrict__ labels,
                                           float* __restrict__ out,
                                           float* __restrict__ rowloss,
                                           int rowidx) {
    constexpr int WAVES = NT / 64;
    __shared__ float w0s[WAVES], w14s[WAVES];
    __shared__ int cnt;
    __shared__ float zz[WAVES], r0s[WAVES], r1s[WAVES], r2s[WAVES];

    const int t = threadIdx.x;
    const int lane = t & 63, wave = t >> 6;

    float m0 = lst[0], m14 = lst[14];
    #pragma unroll
    for (int off = 32; off > 0; off >>= 1) {
        m0  = fminf(m0,  __shfl_down(m0,  off, 64));
        m14 = fminf(m14, __shfl_down(m14, off, 64));
    }
    if (lane == 0) { w0s[wave] = m0; w14s[wave] = m14; }
    __syncthreads();
    float dmin = w0s[0], ub = w14s[0];
    #pragma unroll
    for (int i = 1; i < WAVES; i++) { dmin = fminf(dmin, w0s[i]); ub = fminf(ub, w14s[i]); }

    unsigned lo = fkey(dmin), hi = fkey(ub);
    int iter = 0;
    while (lo < hi && iter < 34) {
        iter++;
        const unsigned mid = lo + ((hi - lo) >> 1);
        const float fmid = finv(mid);
        int c = 0;
        #pragma unroll
        for (int k = 0; k < 15; k++) c += (lst[k] <= fmid) ? 1 : 0;
        #pragma unroll
        for (int off = 32; off > 0; off >>= 1) c += __shfl_down(c, off, 64);
        __syncthreads();
        if (t == 0) cnt = 0;
        __syncthreads();
        if (lane == 0) atomicAdd(&cnt, c);
        __syncthreads();
        const int total = cnt;
        if (total >= 15) hi = mid; else lo = mid + 1;
    }
    const float kth = finv(hi);

    const float4* rb4 = (const float4*)rowb;
    const int4* lb4 = (const int4*)labels;
    float z = 0.f, s0 = 0.f, s1 = 0.f, s2 = 0.f;
    #pragma unroll
    for (int s = 0; s < N_CELLS / (4 * NT); s++) {
        const int idx = s * NT + t;
        const float4 d4 = rb4[idx];
        const int4 l4 = lb4[idx];
        #pragma unroll
        for (int c2 = 0; c2 < 4; c2++) {
            const float d = (c2 == 0) ? d4.x : (c2 == 1) ? d4.y : (c2 == 2) ? d4.z : d4.w;
            const int lab = (c2 == 0) ? l4.x : (c2 == 1) ? l4.y : (c2 == 2) ? l4.z : l4.w;
            const float w = __expf(dmin - d);
            const float msk = 1.0f / (1.0f + __expf(d - kth));
            const float p = w * msk;
            z  += w;
            s0 += (lab == 0) ? p : 0.f;
            s1 += (lab == 1) ? p : 0.f;
            s2 += (lab == 2) ? p : 0.f;
        }
    }
    #pragma unroll
    for (int off = 32; off > 0; off >>= 1) {
        z  += __shfl_down(z,  off, 64);
        s0 += __shfl_down(s0, off, 64);
        s1 += __shfl_down(s1, off, 64);
        s2 += __shfl_down(s2, off, 64);
    }
    if (lane == 0) { zz[wave] = z; r0s[wave] = s0; r1s[wave] = s1; r2s[wave] = s2; }
    __syncthreads();
    if (t == 0) {
        float Z = 0.f, S0 = 0.f, S1 = 0.f, S2 = 0.f;
        #pragma unroll
        for (int i = 0; i < WAVES; i++) { Z += zz[i]; S0 += r0s[i]; S1 += r1s[i]; S2 += r2s[i]; }
        const float ssum = S0 + S1 + S2;
        const float denom = ssum + 1e-8f * Z;
        const float q0 = S0/denom, q1 = S1/denom, q2 = S2/denom;
        const float H = -(q0*logf(q0+1e-8f) + q1*logf(q1+1e-8f) + q2*logf(q2+1e-8f));
        const float contrib = -(H / (logf(3.0f) + 1e-8f)) * (1.0f / N_CELLS);
        if (rowloss) rowloss[rowidx] = contrib;
        else atomicAdd(out, contrib);
    }
}

// ---------- fused fp32 full-row recompute (exact) ----------
__device__ void process_row(int i,
                            const float* __restrict__ E,
                            const float* __restrict__ norms,
                            const int* __restrict__ labels,
                            float* __restrict__ out,
                            float* __restrict__ rowloss,
                            float* rowb, float* ei) {
    const int t = threadIdx.x;
    __syncthreads();
    for (int k = t; k < DIM; k += 512) ei[k] = E[(size_t)i * DIM + k];
    __syncthreads();
    const float ni = norms[i];

    float lst[15];
    #pragma unroll
    for (int k = 0; k < 15; k++) lst[k] = 3.0e38f;

    for (int s = 0; s < N_CELLS / 512; s++) {
        const int j = s * 512 + t;
        const float* ej = E + (size_t)j * DIM;
        float dot = 0.f;
        #pragma unroll 4
        for (int k = 0; k < DIM; k += 4) {
            float4 e4 = *(const float4*)(ej + k);
            dot += ei[k]*e4.x + ei[k+1]*e4.y + ei[k+2]*e4.z + ei[k+3]*e4.w;
        }
        float d = ni + norms[j] - 2.0f * dot;
        if (j == i) d += 1e10f;
        rowb[j] = d;
        float v = d;
        #pragma unroll
        for (int k = 0; k < 15; k++) {
            float lo2 = fminf(lst[k], v);
            v = fmaxf(lst[k], v);
            lst[k] = lo2;
        }
    }
    finish_row<512>(rowb, lst, labels, out, rowloss, i);
}

// cnt_g == nullptr: tiny-ws full mode (grid N_CELLS, one row per block,
// atomic accumulate to out). cnt_g != nullptr: insurance mode (grid 64):
// scan 128 rows each, process only failed rows (~never), store to rowloss.
__global__ __launch_bounds__(512) void fused_kernel(const float* __restrict__ E,
                                                    const float* __restrict__ norms,
                                                    const int* __restrict__ labels,
                                                    float* __restrict__ out,
                                                    float* __restrict__ rowloss,
                                                    const int* __restrict__ cnt_g) {
    __shared__ float rowb[N_CELLS];
    __shared__ float ei[DIM];
    __shared__ int bad[TILE];
    __shared__ int nbad;
    const int t = threadIdx.x;

    if (cnt_g == nullptr) {
        process_row(blockIdx.x, E, norms, labels, out, nullptr, rowb, ei);
        return;
    }
    if (t == 0) nbad = 0;
    __syncthreads();
    if (t < TILE) {
        const int row = blockIdx.x * TILE + t;
        const int n = cnt_g[row];
        if (n < 15 || n > CAP) bad[atomicAdd(&nbad, 1)] = row;
    }
    __syncthreads();
    const int nb = nbad;
    for (int b = 0; b < nb; b++)
        process_row(bad[b], E, norms, labels, out, rowloss, rowb, ei);
}

// ---------- launcher ----------
// ws: norms 32KB | Efp fp16 8MB | T 32KB | cnt 32KB | rowloss 32KB
//     | Dsamp 32MB | cand 25MB
extern "C" void kernel_launch(void* const* d_in, const int* in_sizes, int n_in,
                              void* d_out, int out_size, void* d_ws, size_t ws_size,
                              hipStream_t stream) {
    const float* E = (const float*)d_in[0];
    const int* labels = (const int*)d_in[1];
    float* out = (float*)d_out;

    char* p = (char*)d_ws;
    float* norms = (float*)p;                 p += 32768;
    unsigned short* Efp = (unsigned short*)p; p += (size_t)N_CELLS * DIM * 2;
    float* T = (float*)p;                     p += 32768;
    int* cnt = (int*)p;                       p += 32768;
    float* rowloss = (float*)p;               p += 32768;
    float* Dsamp = (float*)p;                 p += (size_t)N_CELLS * SAMPLE * 4;
    int2* cand = (int2*)p;                    p += (size_t)N_CELLS * CAP * 8;
    const size_t need = (size_t)(p - (char*)d_ws);

    if (ws_size >= need) {
        prep_kernel<<<N_CELLS / 4, 256, 0, stream>>>(E, Efp, norms, out);
        samp_dist_kernel<<<dim3(SAMPLE / TILE, N_CELLS / TILE), 256, 0, stream>>>(Efp, norms, Dsamp);
        tsel_kernel<<<N_CELLS / 4, 256, 0, stream>>>(Dsamp, T, cnt);
        main_cand_kernel<<<NTRI, 256, 0, stream>>>(Efp, norms, labels, T, cnt, cand);
        final_kernel<<<N_CELLS / 4, 256, 0, stream>>>(cand, cnt, T, rowloss);
        fused_kernel<<<N_CELLS / TILE, 512, 0, stream>>>(E, norms, labels, out, rowloss, cnt);  // insurance
        reduce_kernel<<<1, 512, 0, stream>>>(rowloss, out);
    } else {
        norms_kernel<<<N_CELLS / 4, 256, 0, stream>>>(E, norms, out);
        fused_kernel<<<N_CELLS, 512, 0, stream>>>(E, norms, labels, out, nullptr, nullptr);
    }
}